// Round 2
// baseline (455.093 us; speedup 1.0000x reference)
//
#include <hip/hip_runtime.h>

#define B_ 2
#define S_ 2048
#define D_ 64
#define H_ 8

typedef __bf16 bf16x8 __attribute__((ext_vector_type(8)));
typedef float  f32x16 __attribute__((ext_vector_type(16)));
typedef float  f32x4  __attribute__((ext_vector_type(4)));
typedef unsigned int u32x4 __attribute__((ext_vector_type(4)));

// log2(e) and 0.125*log2(e)
#define C_QK 0.18033688011112042f
#define C_B  1.4426950408889634f

__device__ __forceinline__ unsigned int pkbf(float a, float b) {
    __bf16 x = (__bf16)a, y = (__bf16)b;
    unsigned short ux = __builtin_bit_cast(unsigned short, x);
    unsigned short uy = __builtin_bit_cast(unsigned short, y);
    return (unsigned int)ux | ((unsigned int)uy << 16);
}

__global__ __launch_bounds__(64, 1) void attn_kernel(
    const float* __restrict__ x1, const float* __restrict__ x2,
    const float* __restrict__ x3, const float* __restrict__ x4,
    float* __restrict__ out)
{
    const int lane = threadIdx.x;
    const int lo = lane & 31;
    const int hi = lane >> 5;

    const int bid = blockIdx.x;          // 0..1023
    const int b   = bid >> 9;            // /(H*64)
    const int rem = bid & 511;
    const int h   = rem >> 6;
    const int qt  = rem & 63;
    const int qbase = qt * 32;

    // ---- persistent Q fragments (B-operand of QK mfma) ----
    // slot (hi,i) of chunk kk holds Q[qbase+lo][16*kk + 8*hi + i]
    const float* qrow = x1 + ((size_t)b * S_ + qbase + lo) * D_ + 8 * hi;
    bf16x8 Qf[4];
#pragma unroll
    for (int kk = 0; kk < 4; ++kk) {
        f32x4 qa = *(const f32x4*)(qrow + 16 * kk);
        f32x4 qb = *(const f32x4*)(qrow + 16 * kk + 4);
#pragma unroll
        for (int i = 0; i < 4; ++i) {
            Qf[kk][i]     = (__bf16)qa[i];
            Qf[kk][4 + i] = (__bf16)qb[i];
        }
    }

    // ---- state ----
    f32x16 O0, O1;
#pragma unroll
    for (int i = 0; i < 16; ++i) { O0[i] = 0.f; O1[i] = 0.f; }
    float m_run = -3.0e38f;
    float l_run = 0.f;

    const float* brow = x3 + (((size_t)(b * H_ + h) * S_) + qbase + lo) * S_ + 4 * hi;

    auto load_bias = [&](int t, f32x4* dst) {
        const float* p = brow + t * 32;
#pragma unroll
        for (int g = 0; g < 4; ++g) dst[g] = *(const f32x4*)(p + 8 * g);
    };

    auto mk_pfrag = [&](const float* p) -> bf16x8 {
        // own regs: p[0..3] -> t=(0..3)+4hi (+8*grp), p[4..7] -> +8
        int a0 = (int)pkbf(p[0], p[1]), a1 = (int)pkbf(p[2], p[3]);
        int b0 = (int)pkbf(p[4], p[5]), b1 = (int)pkbf(p[6], p[7]);
        int s0 = hi ? a0 : b0, s1 = hi ? a1 : b1;
        int r0 = __shfl_xor(s0, 32);
        int r1 = __shfl_xor(s1, 32);
        u32x4 f;
        f[0] = (unsigned int)(hi ? r0 : a0);
        f[1] = (unsigned int)(hi ? r1 : a1);
        f[2] = (unsigned int)(hi ? b0 : r0);
        f[3] = (unsigned int)(hi ? b1 : r1);
        return __builtin_bit_cast(bf16x8, f);
    };

    auto compute = [&](int t, const f32x4* bias) {
        const int tb = t * 32;

        // --- K tile loads (L2-resident), A-operand slot (hi,i): K[tb+lo][16kk+8hi+i]
        const float* krow = x2 + ((size_t)b * S_ + tb + lo) * D_ + 8 * hi;
        f32x4 kraw[8];
#pragma unroll
        for (int kk = 0; kk < 4; ++kk) {
            kraw[2 * kk]     = *(const f32x4*)(krow + 16 * kk);
            kraw[2 * kk + 1] = *(const f32x4*)(krow + 16 * kk + 4);
        }
        // --- V raw loads issued early: V[tb+16*g2+8*hi+i][32*dh+lo]
        float vraw[4][8];
#pragma unroll
        for (int g2 = 0; g2 < 2; ++g2) {
#pragma unroll
            for (int dh = 0; dh < 2; ++dh) {
                const float* vb = x4 + ((size_t)b * S_ + tb + 16 * g2 + 8 * hi) * D_ + 32 * dh + lo;
#pragma unroll
                for (int i = 0; i < 8; ++i) vraw[2 * g2 + dh][i] = vb[i * D_];
            }
        }

        // --- QK^T (S^T tile: D[r=t][c=q])
        f32x16 acc;
#pragma unroll
        for (int i = 0; i < 16; ++i) acc[i] = 0.f;
#pragma unroll
        for (int kk = 0; kk < 4; ++kk) {
            bf16x8 kf;
#pragma unroll
            for (int i = 0; i < 4; ++i) {
                kf[i]     = (__bf16)kraw[2 * kk][i];
                kf[4 + i] = (__bf16)kraw[2 * kk + 1][i];
            }
            acc = __builtin_amdgcn_mfma_f32_32x32x16_bf16(kf, Qf[kk], acc, 0, 0, 0);
        }

        // --- scores in log2 domain: s = (qk/8 + bias) * log2e
        float s[16];
#pragma unroll
        for (int r = 0; r < 16; ++r)
            s[r] = acc[r] * C_QK + bias[r >> 2][r & 3] * C_B;

        float pmax = s[0];
#pragma unroll
        for (int r = 1; r < 16; ++r) pmax = fmaxf(pmax, s[r]);
        pmax = fmaxf(pmax, __shfl_xor(pmax, 32));

        if (__any(pmax > m_run)) {
            float mnew = fmaxf(m_run, pmax);
            float sc = __builtin_amdgcn_exp2f(m_run - mnew);
#pragma unroll
            for (int r = 0; r < 16; ++r) { O0[r] *= sc; O1[r] *= sc; }
            l_run *= sc;
            m_run = mnew;
        }

        float p[16];
        float ls = 0.f;
#pragma unroll
        for (int r = 0; r < 16; ++r) {
            p[r] = __builtin_amdgcn_exp2f(s[r] - m_run);
            ls += p[r];
        }
        l_run += ls;

        // --- PV: O^T += V^T @ P^T, two t-16 tiles x two d-halves
#pragma unroll
        for (int g2 = 0; g2 < 2; ++g2) {
            bf16x8 pf = mk_pfrag(p + 8 * g2);
#pragma unroll
            for (int dh = 0; dh < 2; ++dh) {
                bf16x8 vf;
#pragma unroll
                for (int i = 0; i < 8; ++i) vf[i] = (__bf16)vraw[2 * g2 + dh][i];
                if (dh == 0) O0 = __builtin_amdgcn_mfma_f32_32x32x16_bf16(vf, pf, O0, 0, 0, 0);
                else         O1 = __builtin_amdgcn_mfma_f32_32x32x16_bf16(vf, pf, O1, 0, 0, 0);
            }
        }
    };

    // ---- main loop with bias prefetch (distance 1) ----
    f32x4 bA[4], bB[4];
    load_bias(0, bA);
    for (int t = 0; t < 64; t += 2) {
        load_bias(t + 1, bB);
        compute(t, bA);
        if (t + 2 < 64) load_bias(t + 2, bA);
        compute(t + 1, bB);
    }

    // ---- epilogue: normalize + store ----
    float Lt = l_run + __shfl_xor(l_run, 32);
    float inv = 1.0f / Lt;

    float* orow = out + (((size_t)(b * H_ + h) * S_) + qbase + lo) * D_;
#pragma unroll
    for (int g = 0; g < 4; ++g) {
        f32x4 w0, w1;
#pragma unroll
        for (int j = 0; j < 4; ++j) {
            w0[j] = O0[4 * g + j] * inv;
            w1[j] = O1[4 * g + j] * inv;
        }
        *(f32x4*)(orow + 8 * g + 4 * hi)      = w0;
        *(f32x4*)(orow + 32 + 8 * g + 4 * hi) = w1;
    }
}

extern "C" void kernel_launch(void* const* d_in, const int* in_sizes, int n_in,
                              void* d_out, int out_size, void* d_ws, size_t ws_size,
                              hipStream_t stream) {
    const float* x1 = (const float*)d_in[0];
    const float* x2 = (const float*)d_in[1];
    const float* x3 = (const float*)d_in[2];
    const float* x4 = (const float*)d_in[3];
    float* o = (float*)d_out;
    hipLaunchKernelGGL(attn_kernel, dim3(B_ * H_ * (S_ / 32)), dim3(64), 0, stream,
                       x1, x2, x3, x4, o);
}